// Round 8
// baseline (765.376 us; speedup 1.0000x reference)
//
#include <hip/hip_runtime.h>
#include <math.h>

static constexpr int D   = 128;
static constexpr int DFF = 512;
static constexpr int LAYERS = 3;
static constexpr float CLAMP_V = 5.0f;
static constexpr float LN_EPS = 1e-5f;

typedef unsigned short u16;
typedef unsigned int   u32;
typedef short bf16x8 __attribute__((ext_vector_type(8)));
typedef float f32x4  __attribute__((ext_vector_type(4)));

__device__ inline float4 ld4(const float* p){ return *reinterpret_cast<const float4*>(p); }
__device__ inline u16 f2bf(float f){ u32 u = __float_as_uint(f); return (u16)((u + 0x7fff + ((u>>16)&1)) >> 16); }
__device__ inline float bl(u32 u){ return __uint_as_float(u << 16); }
__device__ inline float bh(u32 u){ return __uint_as_float(u & 0xffff0000u); }

__device__ inline void gload_lds16(const void* g, void* l) {
  __builtin_amdgcn_global_load_lds(
      (const __attribute__((address_space(1))) void*)g,
      (__attribute__((address_space(3))) void*)l, 16, 0, 0);
}

// ---------------- CSR build ----------------
__global__ __launch_bounds__(256) void count_kernel(const int* __restrict__ dst,
                                                    int* __restrict__ deg, int E)
{
  int e = blockIdx.x*256 + threadIdx.x;
  if (e < E) atomicAdd(&deg[dst[e]], 1);
}

__global__ __launch_bounds__(256) void scan_bsum(const int* __restrict__ deg,
                                                 int* __restrict__ bsum, int N)
{
  const int i0 = blockIdx.x*1024 + threadIdx.x*4;
  int s = 0;
  if (i0 + 3 < N) { int4 v = *(const int4*)&deg[i0]; s = v.x+v.y+v.z+v.w; }
  else { for (int t = 0; t < 4; t++) if (i0+t < N) s += deg[i0+t]; }
  #pragma unroll
  for (int off = 1; off < 64; off <<= 1) s += __shfl_xor(s, off);
  __shared__ int ws_[4];
  if ((threadIdx.x & 63) == 0) ws_[threadIdx.x >> 6] = s;
  __syncthreads();
  if (threadIdx.x == 0) bsum[blockIdx.x] = ws_[0]+ws_[1]+ws_[2]+ws_[3];
}

__global__ __launch_bounds__(64) void scan_bbase(int* __restrict__ bsum, int NB)
{
  const int tid = threadIdx.x;
  int base = 0;
  for (int c = 0; c < NB; c += 64) {
    const int idx = c + tid;
    int v = (idx < NB) ? bsum[idx] : 0;
    const int orig = v;
    #pragma unroll
    for (int off = 1; off < 64; off <<= 1) {
      int t = __shfl_up(v, off);
      if (tid >= off) v += t;
    }
    if (idx < NB) bsum[idx] = base + v - orig;
    base += __shfl(v, 63);
  }
}

__global__ __launch_bounds__(256) void scan_write(const int* __restrict__ deg,
    const int* __restrict__ bbase, int* __restrict__ offs, int* __restrict__ cursor, int N)
{
  const int i0 = blockIdx.x*1024 + threadIdx.x*4;
  int v[4] = {0,0,0,0};
  if (i0 + 3 < N) { int4 t = *(const int4*)&deg[i0]; v[0]=t.x; v[1]=t.y; v[2]=t.z; v[3]=t.w; }
  else { for (int t = 0; t < 4; t++) if (i0+t < N) v[t] = deg[i0+t]; }
  const int s = v[0]+v[1]+v[2]+v[3];
  const int lane = threadIdx.x & 63, w = threadIdx.x >> 6;
  int inc = s;
  #pragma unroll
  for (int off = 1; off < 64; off <<= 1) {
    int t = __shfl_up(inc, off);
    if (lane >= off) inc += t;
  }
  __shared__ int wsum[4];
  if (lane == 63) wsum[w] = inc;
  __syncthreads();
  int wb = 0;
  for (int t = 0; t < 4; t++) if (t < w) wb += wsum[t];
  int run = bbase[blockIdx.x] + wb + inc - s;
  #pragma unroll
  for (int t = 0; t < 4; t++) {
    if (i0 + t < N) { offs[i0+t] = run; cursor[i0+t] = run; run += v[t]; }
  }
  if (i0 <= N-1 && N-1 < i0+4) offs[N] = run;
}

__global__ __launch_bounds__(256) void fill_kernel(const int* __restrict__ dst,
    const int* __restrict__ src, int* __restrict__ cursor, int* __restrict__ csr_src, int E)
{
  int e = blockIdx.x*256 + threadIdx.x;
  if (e < E) {
    int p = atomicAdd(&cursor[dst[e]], 1);
    csr_src[p] = src[e];
  }
}

// ---------------- weight conversion to bf16 ----------------
__global__ __launch_bounds__(256) void convert_weights(
    const float* __restrict__ Wq, const float* __restrict__ Wk, const float* __restrict__ Wv,
    const float* __restrict__ Wo, const float* __restrict__ W1, const float* __restrict__ W2,
    u16* __restrict__ out)
{
  const int SQKV = 3*384*128;
  const int SWO  = 3*128*128;
  const int SW1  = 3*512*128;
  const int SW2  = 3*128*512;
  int i = blockIdx.x*256 + threadIdx.x;
  if (i >= SQKV+SWO+SW1+SW2) return;
  float v;
  if (i < SQKV) {
    int l = i / (384*128), rem = i % (384*128);
    int row = rem / 128, col = rem % 128;
    const float* W = (row < 128) ? Wq : ((row < 256) ? Wk : Wv);
    v = W[(size_t)l*128*128 + (size_t)(row & 127)*128 + col];
  } else if (i < SQKV+SWO) {
    v = Wo[i - SQKV];
  } else if (i < SQKV+SWO+SW1) {
    v = W1[i - SQKV - SWO];
  } else {
    v = W2[i - SQKV - SWO - SW1];
  }
  out[i] = f2bf(v);
}

// ---------------- MFMA helper: A [64][128] swizzled, B [128][64]; 2x4 acc ----------------
__device__ inline void mfma_stage64(const u16* __restrict__ Atile, const u16* __restrict__ Btile,
                                    int lane, int wr, int wc, int kabase, f32x4 (&acc)[2][4])
{
  #pragma unroll
  for (int k2 = 0; k2 < 2; k2++) {
    const int kql = k2*4 + (lane >> 4);
    const int kqa = kabase + kql;
    bf16x8 af[2], bfr[4];
    #pragma unroll
    for (int mi = 0; mi < 2; mi++) {
      const int r = wr*32 + mi*16 + (lane & 15);
      const int slot = ((kqa & 7) ^ (r & 7)) | (kqa & 8);
      af[mi] = *(const bf16x8*)&Atile[r*128 + slot*8];
    }
    #pragma unroll
    for (int ni = 0; ni < 4; ni++) {
      const int r = wc*64 + ni*16 + (lane & 15);
      bfr[ni] = *(const bf16x8*)&Btile[r*64 + ((kql ^ (r & 7)) << 3)];
    }
    #pragma unroll
    for (int mi = 0; mi < 2; mi++)
      #pragma unroll
      for (int ni = 0; ni < 4; ni++)
        acc[mi][ni] = __builtin_amdgcn_mfma_f32_16x16x32_bf16(af[mi], bfr[ni], acc[mi][ni], 0, 0, 0);
  }
}

// ---------------- encoder + layer-0 QKV fused ----------------
__global__ __launch_bounds__(256) void enc_qkv(
    const float* __restrict__ nf, const float* __restrict__ encW, const float* __restrict__ encb,
    const u16* __restrict__ Wqkv,
    float* __restrict__ hf, float* __restrict__ qf, u16* __restrict__ kvb, int M)
{
  __shared__ u16 lB[2][128*64];
  __shared__ u16 h1s[64*128];

  const int tid  = threadIdx.x;
  const int lane = tid & 63;
  const int wid  = tid >> 6;
  const int wr   = wid >> 1, wc = wid & 1;
  const int m0   = blockIdx.x * 64;
  const int ldrow = lane >> 3;
  const int gran  = (lane & 7) ^ ldrow;
  const int rbase_l = wr*32 + ((lane >> 4) << 2);
  const int cbase   = wc*64 + (lane & 15);

  auto stage_issue = [&](int s) {
    u16* dst = lB[s & 1];
    const u16* Bm = Wqkv + (size_t)(s >> 1)*128*128;
    const int k0 = (s & 1)*64 + gran*8;
    #pragma unroll
    for (int is = 0; is < 4; is++) {
      const int r = wid*32 + is*8;
      gload_lds16(Bm + (size_t)(r + ldrow)*128 + k0, dst + r*64);
    }
  };
  stage_issue(0);

  // encoder: h = nf @ encW^T + encb (VALU, K=16), acc layout matches MFMA C layout
  f32x4 hacc[2][4];
  #pragma unroll
  for (int mi = 0; mi < 2; mi++) {
    #pragma unroll
    for (int r = 0; r < 4; r++) {
      const int lrow = rbase_l + mi*16 + r;
      int grow = m0 + lrow; if (grow >= M) grow = M - 1;
      const float* nr = nf + (size_t)grow*16;
      float nfr[16];
      #pragma unroll
      for (int t = 0; t < 4; t++) *(float4*)&nfr[t*4] = ld4(&nr[t*4]);
      #pragma unroll
      for (int ni = 0; ni < 4; ni++) {
        const int col = cbase + ni*16;
        const float* wrow = encW + (size_t)col*16;
        float s = encb[col];
        #pragma unroll
        for (int kk = 0; kk < 16; kk++) s = fmaf(nfr[kk], wrow[kk], s);
        hacc[mi][ni][r] = s;
      }
    }
  }
  // write hf + h1s (bf16 swizzled)
  #pragma unroll
  for (int mi = 0; mi < 2; mi++) {
    #pragma unroll
    for (int r = 0; r < 4; r++) {
      const int lrow = rbase_l + mi*16 + r;
      const int grow = m0 + lrow;
      #pragma unroll
      for (int ni = 0; ni < 4; ni++) {
        const int col = cbase + ni*16;
        const float o = hacc[mi][ni][r];
        if (grow < M) hf[(size_t)grow*128 + col] = o;
        const int g16 = col >> 3;
        const int slot = ((g16 & 7) ^ (lrow & 7)) | (g16 & 8);
        h1s[lrow*128 + slot*8 + (col & 7)] = f2bf(o);
      }
    }
  }
  asm volatile("s_waitcnt vmcnt(0)" ::: "memory");
  __syncthreads();

  f32x4 acc[2][4];
  #pragma unroll
  for (int s = 0; s < 6; s++) {
    if (s < 5) stage_issue(s + 1);
    if ((s & 1) == 0) {
      #pragma unroll
      for (int i = 0; i < 2; i++)
        #pragma unroll
        for (int j = 0; j < 4; j++) { acc[i][j][0]=0.f; acc[i][j][1]=0.f; acc[i][j][2]=0.f; acc[i][j][3]=0.f; }
    }
    mfma_stage64(h1s, lB[s & 1], lane, wr, wc, (s & 1)*8, acc);
    if (s & 1) {
      const int mat = s >> 1;
      #pragma unroll
      for (int mi = 0; mi < 2; mi++) {
        #pragma unroll
        for (int r = 0; r < 4; r++) {
          const int grow = m0 + rbase_l + mi*16 + r;
          if (grow >= M) continue;
          #pragma unroll
          for (int ni = 0; ni < 4; ni++) {
            const int col = cbase + ni*16;
            if (mat == 0) qf[(size_t)grow*128 + col] = acc[mi][ni][r];
            else          kvb[(size_t)grow*256 + (mat-1)*128 + col] = f2bf(acc[mi][ni][r]);
          }
        }
      }
    }
    if (s < 5) {
      asm volatile("s_waitcnt vmcnt(0)" ::: "memory");
      __syncthreads();
    }
  }
}

// ---------------- fused per-layer tail (+ optional next-layer QKV) ----------------
template<bool QKV>
__global__ __launch_bounds__(256) void ffn_fused(
    const u16* __restrict__ savb, const u16* __restrict__ Wo,
    const u16* __restrict__ W1,   const u16* __restrict__ W2,
    const u16* __restrict__ Wqkv,
    const float* __restrict__ ln1g, const float* __restrict__ ln1b,
    const float* __restrict__ b1,   const float* __restrict__ b2,
    const float* __restrict__ ln2g, const float* __restrict__ ln2b,
    float* __restrict__ hf, float* __restrict__ qf, u16* __restrict__ kvb, int M)
{
  __shared__ u16 lB[2][128*64];
  __shared__ u16 h1s[64*128];
  __shared__ u16 fs[64*128];
  __shared__ float lsum[64][2];
  __shared__ float lsq[64][2];

  const int tid  = threadIdx.x;
  const int lane = tid & 63;
  const int wid  = tid >> 6;
  const int wr   = wid >> 1, wc = wid & 1;
  const int m0   = blockIdx.x * 64;

  const int ldrow = lane >> 3;
  const int gran  = (lane & 7) ^ ldrow;

  const int rbase_l = wr*32 + ((lane >> 4) << 2);
  const int cbase   = wc*64 + (lane & 15);

  constexpr int NS = QKV ? 24 : 18;

  auto stage_issue = [&](int s) {
    u16* dst = lB[s & 1];
    #pragma unroll
    for (int is = 0; is < 4; is++) {
      const int r = wid*32 + is*8;
      const u16* gp;
      if (s < 2) gp = Wo + (size_t)(r + ldrow)*128 + s*64;
      else if (s < 18) {
        const int t = s - 2, c = t >> 2, k = t & 3;
        gp = (k < 2) ? (W1 + (size_t)(c*128 + r + ldrow)*128 + k*64)
                     : (W2 + (size_t)(r + ldrow)*512 + c*128 + (k-2)*64);
      } else {
        const int t = s - 18, mat = t >> 1, k = t & 1;
        gp = Wqkv + (size_t)mat*128*128 + (size_t)(r + ldrow)*128 + k*64;
      }
      gload_lds16(gp + gran*8, dst + r*64);
    }
  };

  #pragma unroll
  for (int is = 0; is < 4; is++) {
    const int r0 = wid*16 + is*4;
    const int rr = r0 + (lane >> 4);
    int gm = m0 + rr; if (gm >= M) gm = M - 1;
    const int gsrc = ((lane & 7) ^ (rr & 7)) | (lane & 8);
    gload_lds16(savb + (size_t)gm*128 + gsrc*8, &fs[r0*128]);
  }
  stage_issue(0);

  f32x4 acc1[2][4], acc2[2][4], acc3[2][4];
  #pragma unroll
  for (int i = 0; i < 2; i++)
    #pragma unroll
    for (int j = 0; j < 4; j++) {
      acc1[i][j][0]=0.f; acc1[i][j][1]=0.f; acc1[i][j][2]=0.f; acc1[i][j][3]=0.f;
      acc3[i][j][0]=0.f; acc3[i][j][1]=0.f; acc3[i][j][2]=0.f; acc3[i][j][3]=0.f;
    }

  asm volatile("s_waitcnt vmcnt(0)" ::: "memory");
  __syncthreads();

  #pragma unroll
  for (int s = 0; s < NS; s++) {
    if (s < NS-1) stage_issue(s + 1);

    // acc2 reset at starts
    if ((s >= 2 && s < 18 && ((s - 2) & 3) == 0) || (s >= 18 && ((s - 18) & 1) == 0)) {
      #pragma unroll
      for (int i = 0; i < 2; i++)
        #pragma unroll
        for (int j = 0; j < 4; j++) { acc2[i][j][0]=0.f; acc2[i][j][1]=0.f; acc2[i][j][2]=0.f; acc2[i][j][3]=0.f; }
    }

    if (s < 2)
      mfma_stage64(fs,  lB[s & 1], lane, wr, wc, (s & 1)*8, acc1);
    else if (s < 18) {
      if (((s - 2) & 3) < 2)
        mfma_stage64(h1s, lB[s & 1], lane, wr, wc, (s & 1)*8, acc2);
      else
        mfma_stage64(fs,  lB[s & 1], lane, wr, wc, (s & 1)*8, acc3);
    } else
      mfma_stage64(h1s, lB[s & 1], lane, wr, wc, (s & 1)*8, acc2);

    if (s == 1) {
      // LN1: x = uh + h_res ; h1 -> acc1 (f32) + h1s (bf16)
      #pragma unroll
      for (int mi = 0; mi < 2; mi++) {
        #pragma unroll
        for (int r = 0; r < 4; r++) {
          const int lrow = rbase_l + mi*16 + r;
          int gr = m0 + lrow; if (gr >= M) gr = M - 1;
          float ps = 0.f, pq = 0.f;
          #pragma unroll
          for (int ni = 0; ni < 4; ni++) {
            const int col = cbase + ni*16;
            float x = acc1[mi][ni][r] + hf[(size_t)gr*128 + col];
            acc1[mi][ni][r] = x;
            ps += x; pq += x*x;
          }
          #pragma unroll
          for (int off = 1; off < 16; off <<= 1) { ps += __shfl_xor(ps, off); pq += __shfl_xor(pq, off); }
          if ((lane & 15) == 0) { lsum[lrow][wc] = ps; lsq[lrow][wc] = pq; }
        }
      }
      __syncthreads();
      #pragma unroll
      for (int mi = 0; mi < 2; mi++) {
        #pragma unroll
        for (int r = 0; r < 4; r++) {
          const int lrow = rbase_l + mi*16 + r;
          const float mean = (lsum[lrow][0] + lsum[lrow][1]) * (1.0f/128.0f);
          float var = (lsq[lrow][0] + lsq[lrow][1]) * (1.0f/128.0f) - mean*mean;
          const float rstd = rsqrtf(fmaxf(var, 0.f) + LN_EPS);
          #pragma unroll
          for (int ni = 0; ni < 4; ni++) {
            const int col = cbase + ni*16;
            float o = (acc1[mi][ni][r] - mean) * rstd * ln1g[col] + ln1b[col];
            acc1[mi][ni][r] = o;
            const int g16 = col >> 3;
            const int slot = ((g16 & 7) ^ (lrow & 7)) | (g16 & 8);
            h1s[lrow*128 + slot*8 + (col & 7)] = f2bf(o);
          }
        }
      }
    } else if (s >= 2 && s < 18 && ((s - 2) & 3) == 1) {
      const int c = (s - 2) >> 2;
      #pragma unroll
      for (int mi = 0; mi < 2; mi++) {
        #pragma unroll
        for (int r = 0; r < 4; r++) {
          const int lrow = rbase_l + mi*16 + r;
          #pragma unroll
          for (int ni = 0; ni < 4; ni++) {
            const int col = cbase + ni*16;
            float v = fmaxf(acc2[mi][ni][r] + b1[c*128 + col], 0.f);
            const int g16 = col >> 3;
            const int slot = ((g16 & 7) ^ (lrow & 7)) | (g16 & 8);
            fs[lrow*128 + slot*8 + (col & 7)] = f2bf(v);
          }
        }
      }
    } else if (s == 17) {
      // LN2: h = LN2(h1 + ffn2 + b2) -> hf (+ h1s bf16 if QKV)
      #pragma unroll
      for (int mi = 0; mi < 2; mi++) {
        #pragma unroll
        for (int r = 0; r < 4; r++) {
          const int lrow = rbase_l + mi*16 + r;
          float ps = 0.f, pq = 0.f;
          #pragma unroll
          for (int ni = 0; ni < 4; ni++) {
            const int col = cbase + ni*16;
            float x = acc3[mi][ni][r] + b2[col] + acc1[mi][ni][r];
            acc3[mi][ni][r] = x;
            ps += x; pq += x*x;
          }
          #pragma unroll
          for (int off = 1; off < 16; off <<= 1) { ps += __shfl_xor(ps, off); pq += __shfl_xor(pq, off); }
          if ((lane & 15) == 0) { lsum[lrow][wc] = ps; lsq[lrow][wc] = pq; }
        }
      }
      __syncthreads();
      #pragma unroll
      for (int mi = 0; mi < 2; mi++) {
        #pragma unroll
        for (int r = 0; r < 4; r++) {
          const int lrow = rbase_l + mi*16 + r;
          const int grow = m0 + lrow;
          const float mean = (lsum[lrow][0] + lsum[lrow][1]) * (1.0f/128.0f);
          float var = (lsq[lrow][0] + lsq[lrow][1]) * (1.0f/128.0f) - mean*mean;
          const float rstd = rsqrtf(fmaxf(var, 0.f) + LN_EPS);
          #pragma unroll
          for (int ni = 0; ni < 4; ni++) {
            const int col = cbase + ni*16;
            float o = (acc3[mi][ni][r] - mean) * rstd * ln2g[col] + ln2b[col];
            if (grow < M) hf[(size_t)grow*128 + col] = o;
            if (QKV) {
              const int g16 = col >> 3;
              const int slot = ((g16 & 7) ^ (lrow & 7)) | (g16 & 8);
              h1s[lrow*128 + slot*8 + (col & 7)] = f2bf(o);
            }
          }
        }
      }
    } else if (QKV && s >= 19 && (s & 1)) {
      const int mat = (s - 19) >> 1;
      #pragma unroll
      for (int mi = 0; mi < 2; mi++) {
        #pragma unroll
        for (int r = 0; r < 4; r++) {
          const int grow = m0 + rbase_l + mi*16 + r;
          if (grow >= M) continue;
          #pragma unroll
          for (int ni = 0; ni < 4; ni++) {
            const int col = cbase + ni*16;
            if (mat == 0) qf[(size_t)grow*128 + col] = acc2[mi][ni][r];
            else          kvb[(size_t)grow*256 + (mat-1)*128 + col] = f2bf(acc2[mi][ni][r]);
          }
        }
      }
    }

    if (s < NS-1) {
      asm volatile("s_waitcnt vmcnt(0)" ::: "memory");
      __syncthreads();
    }
  }
}

// ---------------- attention: single-pass, constant-shift softmax, 8-deep MLP ----------------
__global__ __launch_bounds__(256) void attn_kernel(
    const float* __restrict__ q, const u16* __restrict__ kv,
    const int* __restrict__ offs, const int* __restrict__ csr_src,
    u16* __restrict__ outb, int N)
{
  const int tid = threadIdx.x;
  const int j   = tid & 15;
  const int n   = blockIdx.x*16 + (tid >> 4);
  if (n >= N) return;

  float qreg[8];
  *(float4*)&qreg[0] = ld4(&q[(size_t)n*128 + j*8]);
  *(float4*)&qreg[4] = ld4(&q[(size_t)n*128 + j*8 + 4]);

  const int start = offs[n];
  const int deg   = offs[n+1] - start;

  float s = 0.f;
  float acc[8] = {0,0,0,0,0,0,0,0};
  const int gb = tid & 48;

  for (int base = 0; base < deg; base += 16) {
    const int myidx = base + j;
    const int sn_mine = (myidx < deg) ? csr_src[start + myidx] : 0;
    const int cnt = (deg - base < 16) ? (deg - base) : 16;

    for (int b2 = 0; b2 < cnt; b2 += 8) {
      const int m8 = cnt - b2;
      uint4 K4[8], V4[8];
      #pragma unroll
      for (int u = 0; u < 8; u++) {
        const int sel = b2 + ((u < m8) ? u : 0);
        const int sn = __shfl(sn_mine, gb + sel);
        const u16* row = kv + (size_t)sn*256 + j*8;
        K4[u] = *(const uint4*)row;
        V4[u] = *(const uint4*)(row + 128);
      }
      #pragma unroll
      for (int u = 0; u < 8; u++) {
        if (u < m8) {
          float d = bl(K4[u].x)*qreg[0] + bh(K4[u].x)*qreg[1]
                  + bl(K4[u].y)*qreg[2] + bh(K4[u].y)*qreg[3]
                  + bl(K4[u].z)*qreg[4] + bh(K4[u].z)*qreg[5]
                  + bl(K4[u].w)*qreg[6] + bh(K4[u].w)*qreg[7];
          d += __shfl_xor(d, 1);
          float uu = fminf(fmaxf(d * 0.25f, -CLAMP_V), CLAMP_V);
          float e = __expf(uu - CLAMP_V);
          s += e;
          acc[0] = fmaf(e, bl(V4[u].x), acc[0]);
          acc[1] = fmaf(e, bh(V4[u].x), acc[1]);
          acc[2] = fmaf(e, bl(V4[u].y), acc[2]);
          acc[3] = fmaf(e, bh(V4[u].y), acc[3]);
          acc[4] = fmaf(e, bl(V4[u].z), acc[4]);
          acc[5] = fmaf(e, bh(V4[u].z), acc[5]);
          acc[6] = fmaf(e, bl(V4[u].w), acc[6]);
          acc[7] = fmaf(e, bh(V4[u].w), acc[7]);
        }
      }
    }
  }

  const float rs = (deg > 0) ? (1.0f / s) : 0.f;
  u16 o[8];
  #pragma unroll
  for (int t = 0; t < 8; t++) o[t] = f2bf(acc[t] * rs);
  *(uint4*)&outb[(size_t)n*128 + j*8] = *(const uint4*)o;
}

// ---------------- decoder + mean ----------------
__global__ __launch_bounds__(256) void dec_partial(const float* __restrict__ h,
    const float* __restrict__ W, float* __restrict__ partials, int N)
{
  float acc = 0.f;
  for (int n = blockIdx.x*256 + threadIdx.x; n < N; n += 256*256) {
    const float* hr = h + (size_t)n*D;
    float s = 0.f;
    #pragma unroll
    for (int t = 0; t < 32; t++) {
      float4 hv = ld4(&hr[t*4]); float4 wv = ld4(&W[t*4]);
      s += hv.x*wv.x + hv.y*wv.y + hv.z*wv.z + hv.w*wv.w;
    }
    acc += s;
  }
  #pragma unroll
  for (int off = 1; off < 64; off <<= 1) acc += __shfl_xor(acc, off);
  __shared__ float red[4];
  int lane = threadIdx.x & 63, w = threadIdx.x >> 6;
  if (lane == 0) red[w] = acc;
  __syncthreads();
  if (threadIdx.x == 0) partials[blockIdx.x] = red[0]+red[1]+red[2]+red[3];
}

__global__ __launch_bounds__(256) void dec_final(const float* __restrict__ partials,
    const float* __restrict__ decb, float* __restrict__ out, int N)
{
  float a = partials[threadIdx.x];
  #pragma unroll
  for (int off = 1; off < 64; off <<= 1) a += __shfl_xor(a, off);
  __shared__ float red[4];
  int lane = threadIdx.x & 63, w = threadIdx.x >> 6;
  if (lane == 0) red[w] = a;
  __syncthreads();
  if (threadIdx.x == 0) out[0] = (red[0]+red[1]+red[2]+red[3]) / (float)N + decb[0];
}

// ---------------- launch ----------------
extern "C" void kernel_launch(void* const* d_in, const int* in_sizes, int n_in,
                              void* d_out, int out_size, void* d_ws, size_t ws_size,
                              hipStream_t stream)
{
  const float* nf   = (const float*)d_in[0];
  const int*   src  = (const int*)  d_in[1];
  const int*   dst  = (const int*)  d_in[2];
  const float* encW = (const float*)d_in[3];
  const float* encb = (const float*)d_in[4];
  const float* Wq   = (const float*)d_in[5];
  const float* Wk   = (const float*)d_in[6];
  const float* Wv   = (const float*)d_in[7];
  const float* Wo   = (const float*)d_in[8];
  const float* ln1g = (const float*)d_in[9];
  const float* ln1b = (const float*)d_in[10];
  const float* W1   = (const float*)d_in[11];
  const float* b1   = (const float*)d_in[12];
  const float* W2   = (const float*)d_in[13];
  const float* b2   = (const float*)d_in[14];
  const float* ln2g = (const float*)d_in[15];
  const float* ln2b = (const float*)d_in[16];
  const float* decW = (const float*)d_in[17];
  const float* decb = (const float*)d_in[18];
  float* out = (float*)d_out;

  const int N = in_sizes[0] / 16;
  const int E = in_sizes[1];
  const int NB = (N + 1023) / 1024;

  float* ws   = (float*)d_ws;
  float* h    = ws;                              // [N,128] f32
  float* q    = h  + (size_t)N*128;              // [N,128] f32
  u16*  kvb   = (u16*)(q + (size_t)N*128);       // [N,256] bf16 (k | v)
  u16*  savb  = kvb + (size_t)N*256;             // [N,128] bf16 (attn out)
  int* deg    = (int*)(savb + (size_t)N*128);
  int* offs   = deg + N;
  int* cursor = offs + N + 1;
  int* csr    = cursor + N;                      // holds src-node ids
  int* bsum   = csr + E;
  float* partials = (float*)(bsum + ((NB + 255) & ~255));
  u16* wbuf   = (u16*)(partials + 512);          // bf16 weights
  u16* wqkv   = wbuf;                            // [3][384][128]
  u16* wo_b   = wbuf + 147456;                   // [3][128][128]
  u16* w1_b   = wbuf + 196608;                   // [3][512][128]
  u16* w2_b   = wbuf + 393216;                   // [3][128][512]

  hipMemsetAsync(deg, 0, sizeof(int)*N, stream);
  count_kernel<<<(E+255)/256, 256, 0, stream>>>(dst, deg, E);
  scan_bsum<<<NB, 256, 0, stream>>>(deg, bsum, N);
  scan_bbase<<<1, 64, 0, stream>>>(bsum, NB);
  scan_write<<<NB, 256, 0, stream>>>(deg, bsum, offs, cursor, N);
  fill_kernel<<<(E+255)/256, 256, 0, stream>>>(dst, src, cursor, csr, E);

  convert_weights<<<(589824+255)/256, 256, 0, stream>>>(Wq, Wk, Wv, Wo, W1, W2, wbuf);

  const int g64 = (N + 63)/64;

  enc_qkv<<<g64, 256, 0, stream>>>(nf, encW, encb, wqkv, h, q, kvb, N);

  for (int l = 0; l < LAYERS; l++) {
    const u16* wo_l   = wo_b + (size_t)l*128*128;
    const u16* w1_l   = w1_b + (size_t)l*512*128;
    const u16* w2_l   = w2_b + (size_t)l*128*512;
    const u16* wqkv_n = wqkv + (size_t)(l+1)*384*128;

    attn_kernel<<<(N+15)/16, 256, 0, stream>>>(q, kvb, offs, csr, savb, N);

    if (l < LAYERS-1)
      ffn_fused<true><<<g64, 256, 0, stream>>>(
          savb, wo_l, w1_l, w2_l, wqkv_n,
          ln1g + l*D, ln1b + l*D, b1 + l*DFF, b2 + l*D, ln2g + l*D, ln2b + l*D,
          h, q, kvb, N);
    else
      ffn_fused<false><<<g64, 256, 0, stream>>>(
          savb, wo_l, w1_l, w2_l, nullptr,
          ln1g + l*D, ln1b + l*D, b1 + l*DFF, b2 + l*D, ln2g + l*D, ln2b + l*D,
          h, nullptr, nullptr, N);
  }

  dec_partial<<<256, 256, 0, stream>>>(h, decW, partials, N);
  dec_final<<<1, 256, 0, stream>>>(partials, decb, out, N);
}

// Round 9
// 541.981 us; speedup vs baseline: 1.4122x; 1.4122x over previous
//
#include <hip/hip_runtime.h>
#include <math.h>

static constexpr int D   = 128;
static constexpr int DFF = 512;
static constexpr int LAYERS = 3;
static constexpr float CLAMP_V = 5.0f;
static constexpr float LN_EPS = 1e-5f;

typedef unsigned short u16;
typedef unsigned int   u32;
typedef short bf16x8 __attribute__((ext_vector_type(8)));
typedef float f32x4  __attribute__((ext_vector_type(4)));

__device__ inline float4 ld4(const float* p){ return *reinterpret_cast<const float4*>(p); }
__device__ inline u16 f2bf(float f){ u32 u = __float_as_uint(f); return (u16)((u + 0x7fff + ((u>>16)&1)) >> 16); }
__device__ inline float bl(u32 u){ return __uint_as_float(u << 16); }
__device__ inline float bh(u32 u){ return __uint_as_float(u & 0xffff0000u); }

__device__ inline void gload_lds16(const void* g, void* l) {
  __builtin_amdgcn_global_load_lds(
      (const __attribute__((address_space(1))) void*)g,
      (__attribute__((address_space(3))) void*)l, 16, 0, 0);
}

// ---------------- CSR build ----------------
__global__ __launch_bounds__(256) void count_kernel(const int* __restrict__ dst,
                                                    int* __restrict__ deg, int E)
{
  int e = blockIdx.x*256 + threadIdx.x;
  if (e < E) atomicAdd(&deg[dst[e]], 1);
}

__global__ __launch_bounds__(256) void scan_bsum(const int* __restrict__ deg,
                                                 int* __restrict__ bsum, int N)
{
  const int i0 = blockIdx.x*1024 + threadIdx.x*4;
  int s = 0;
  if (i0 + 3 < N) { int4 v = *(const int4*)&deg[i0]; s = v.x+v.y+v.z+v.w; }
  else { for (int t = 0; t < 4; t++) if (i0+t < N) s += deg[i0+t]; }
  #pragma unroll
  for (int off = 1; off < 64; off <<= 1) s += __shfl_xor(s, off);
  __shared__ int ws_[4];
  if ((threadIdx.x & 63) == 0) ws_[threadIdx.x >> 6] = s;
  __syncthreads();
  if (threadIdx.x == 0) bsum[blockIdx.x] = ws_[0]+ws_[1]+ws_[2]+ws_[3];
}

__global__ __launch_bounds__(64) void scan_bbase(int* __restrict__ bsum, int NB)
{
  const int tid = threadIdx.x;
  int base = 0;
  for (int c = 0; c < NB; c += 64) {
    const int idx = c + tid;
    int v = (idx < NB) ? bsum[idx] : 0;
    const int orig = v;
    #pragma unroll
    for (int off = 1; off < 64; off <<= 1) {
      int t = __shfl_up(v, off);
      if (tid >= off) v += t;
    }
    if (idx < NB) bsum[idx] = base + v - orig;
    base += __shfl(v, 63);
  }
}

__global__ __launch_bounds__(256) void scan_write(const int* __restrict__ deg,
    const int* __restrict__ bbase, int* __restrict__ offs, int* __restrict__ cursor, int N)
{
  const int i0 = blockIdx.x*1024 + threadIdx.x*4;
  int v[4] = {0,0,0,0};
  if (i0 + 3 < N) { int4 t = *(const int4*)&deg[i0]; v[0]=t.x; v[1]=t.y; v[2]=t.z; v[3]=t.w; }
  else { for (int t = 0; t < 4; t++) if (i0+t < N) v[t] = deg[i0+t]; }
  const int s = v[0]+v[1]+v[2]+v[3];
  const int lane = threadIdx.x & 63, w = threadIdx.x >> 6;
  int inc = s;
  #pragma unroll
  for (int off = 1; off < 64; off <<= 1) {
    int t = __shfl_up(inc, off);
    if (lane >= off) inc += t;
  }
  __shared__ int wsum[4];
  if (lane == 63) wsum[w] = inc;
  __syncthreads();
  int wb = 0;
  for (int t = 0; t < 4; t++) if (t < w) wb += wsum[t];
  int run = bbase[blockIdx.x] + wb + inc - s;
  #pragma unroll
  for (int t = 0; t < 4; t++) {
    if (i0 + t < N) { offs[i0+t] = run; cursor[i0+t] = run; run += v[t]; }
  }
  if (i0 <= N-1 && N-1 < i0+4) offs[N] = run;
}

__global__ __launch_bounds__(256) void fill_kernel(const int* __restrict__ dst,
    const int* __restrict__ src, int* __restrict__ cursor, int* __restrict__ csr_src, int E)
{
  int e = blockIdx.x*256 + threadIdx.x;
  if (e < E) {
    int p = atomicAdd(&cursor[dst[e]], 1);
    csr_src[p] = src[e];
  }
}

// ---------------- weight conversion to bf16 ----------------
__global__ __launch_bounds__(256) void convert_weights(
    const float* __restrict__ Wq, const float* __restrict__ Wk, const float* __restrict__ Wv,
    const float* __restrict__ Wo, const float* __restrict__ W1, const float* __restrict__ W2,
    u16* __restrict__ out)
{
  const int SQKV = 3*384*128;
  const int SWO  = 3*128*128;
  const int SW1  = 3*512*128;
  const int SW2  = 3*128*512;
  int i = blockIdx.x*256 + threadIdx.x;
  if (i >= SQKV+SWO+SW1+SW2) return;
  float v;
  if (i < SQKV) {
    int l = i / (384*128), rem = i % (384*128);
    int row = rem / 128, col = rem % 128;
    const float* W = (row < 128) ? Wq : ((row < 256) ? Wk : Wv);
    v = W[(size_t)l*128*128 + (size_t)(row & 127)*128 + col];
  } else if (i < SQKV+SWO) {
    v = Wo[i - SQKV];
  } else if (i < SQKV+SWO+SW1) {
    v = W1[i - SQKV - SWO];
  } else {
    v = W2[i - SQKV - SWO - SW1];
  }
  out[i] = f2bf(v);
}

// ---------------- encoder (f32 + bf16 dual write) ----------------
__global__ __launch_bounds__(256) void encoder_kernel(
    const float* __restrict__ nf, const float* __restrict__ W,
    const float* __restrict__ b, float* __restrict__ h, u16* __restrict__ hb, int N)
{
  int n = blockIdx.x*2 + (threadIdx.x >> 7);
  int d = threadIdx.x & 127;
  if (n >= N) return;
  const float* nr = nf + (size_t)n*16;
  const float* wr = W  + (size_t)d*16;
  float s = b[d];
  #pragma unroll
  for (int kk = 0; kk < 16; kk++) s = fmaf(nr[kk], wr[kk], s);
  h[(size_t)n*D + d]  = s;
  hb[(size_t)n*D + d] = f2bf(s);
}

// ---------------- MFMA helpers ----------------
__device__ inline void mfma_step128(const u16* __restrict__ la, const u16* __restrict__ lb,
                                    int lane, int wr, int wc, f32x4 (&acc)[4][4])
{
  #pragma unroll
  for (int k2 = 0; k2 < 2; k2++) {
    bf16x8 af[4], bfr[4];
    const int kq = k2*4 + (lane >> 4);
    #pragma unroll
    for (int mi = 0; mi < 4; mi++) {
      const int r = wr*64 + mi*16 + (lane & 15);
      af[mi] = *(const bf16x8*)&la[r*64 + ((kq ^ (r & 7)) << 3)];
    }
    #pragma unroll
    for (int ni = 0; ni < 4; ni++) {
      const int r = wc*64 + ni*16 + (lane & 15);
      bfr[ni] = *(const bf16x8*)&lb[r*64 + ((kq ^ (r & 7)) << 3)];
    }
    #pragma unroll
    for (int mi = 0; mi < 4; mi++)
      #pragma unroll
      for (int ni = 0; ni < 4; ni++)
        acc[mi][ni] = __builtin_amdgcn_mfma_f32_16x16x32_bf16(af[mi], bfr[ni], acc[mi][ni], 0, 0, 0);
  }
}

__device__ inline void mfma_stage64(const u16* __restrict__ Atile, const u16* __restrict__ Btile,
                                    int lane, int wr, int wc, int kabase, f32x4 (&acc)[2][4])
{
  #pragma unroll
  for (int k2 = 0; k2 < 2; k2++) {
    const int kql = k2*4 + (lane >> 4);
    const int kqa = kabase + kql;
    bf16x8 af[2], bfr[4];
    #pragma unroll
    for (int mi = 0; mi < 2; mi++) {
      const int r = wr*32 + mi*16 + (lane & 15);
      const int slot = ((kqa & 7) ^ (r & 7)) | (kqa & 8);
      af[mi] = *(const bf16x8*)&Atile[r*128 + slot*8];
    }
    #pragma unroll
    for (int ni = 0; ni < 4; ni++) {
      const int r = wc*64 + ni*16 + (lane & 15);
      bfr[ni] = *(const bf16x8*)&Btile[r*64 + ((kql ^ (r & 7)) << 3)];
    }
    #pragma unroll
    for (int mi = 0; mi < 2; mi++)
      #pragma unroll
      for (int ni = 0; ni < 4; ni++)
        acc[mi][ni] = __builtin_amdgcn_mfma_f32_16x16x32_bf16(af[mi], bfr[ni], acc[mi][ni], 0, 0, 0);
  }
}

// ---------------- QKV GEMM: A staged once, 3 weight mats streamed ----------------
__global__ __launch_bounds__(256) void gemm_qkv(
    const u16* __restrict__ A, const u16* __restrict__ B,
    float* __restrict__ qf, u16* __restrict__ kvb, int M)
{
  __shared__ u16 lA[2][128*64];
  __shared__ u16 lW[2][128*64];
  const int m0 = blockIdx.x * 128;
  const int tid = threadIdx.x, lane = tid & 63, wid = tid >> 6;
  const int wr = wid >> 1, wc = wid & 1;
  const int ldrow = lane >> 3;
  const int gran  = (lane & 7) ^ ldrow;

  auto issueA = [&](int ks) {
    const int k0 = ks*64 + gran*8;
    #pragma unroll
    for (int is = 0; is < 4; is++) {
      const int r = wid*32 + is*8;
      int gm = m0 + r + ldrow; if (gm >= M) gm = M - 1;
      gload_lds16(A + (size_t)gm*128 + k0, &lA[ks][r*64]);
    }
  };
  auto issueW = [&](int s) {
    const u16* Bm = B + (size_t)(s >> 1)*128*128;
    const int k0 = (s & 1)*64 + gran*8;
    #pragma unroll
    for (int is = 0; is < 4; is++) {
      const int r = wid*32 + is*8;
      gload_lds16(Bm + (size_t)(r + ldrow)*128 + k0, &lW[s & 1][r*64]);
    }
  };

  issueA(0); issueA(1); issueW(0);

  f32x4 acc[4][4];
  const int rbase = m0 + wr*64 + ((lane >> 4) << 2);
  const int cbase = wc*64 + (lane & 15);

  asm volatile("s_waitcnt vmcnt(0)" ::: "memory");
  __syncthreads();

  #pragma unroll
  for (int s = 0; s < 6; s++) {
    if (s < 5) issueW(s + 1);
    if ((s & 1) == 0) {
      #pragma unroll
      for (int i = 0; i < 4; i++)
        #pragma unroll
        for (int j = 0; j < 4; j++) { acc[i][j][0]=0.f; acc[i][j][1]=0.f; acc[i][j][2]=0.f; acc[i][j][3]=0.f; }
    }
    mfma_step128(lA[s & 1], lW[s & 1], lane, wr, wc, acc);
    if (s & 1) {
      const int mat = s >> 1;
      #pragma unroll
      for (int ni = 0; ni < 4; ni++) {
        const int col = cbase + ni*16;
        #pragma unroll
        for (int mi = 0; mi < 4; mi++) {
          #pragma unroll
          for (int r = 0; r < 4; r++) {
            const int gm = rbase + mi*16 + r;
            if (gm < M) {
              if (mat == 0) qf[(size_t)gm*128 + col] = acc[mi][ni][r];
              else          kvb[(size_t)gm*256 + (mat-1)*128 + col] = f2bf(acc[mi][ni][r]);
            }
          }
        }
      }
    }
    if (s < 5) {
      asm volatile("s_waitcnt vmcnt(0)" ::: "memory");
      __syncthreads();
    }
  }
}

// ---------------- fused per-layer tail, 18-stage software pipeline ----------------
__global__ __launch_bounds__(256) void ffn_fused(
    const u16* __restrict__ savb, const u16* __restrict__ Wo,
    const u16* __restrict__ W1,   const u16* __restrict__ W2,
    const float* __restrict__ ln1g, const float* __restrict__ ln1b,
    const float* __restrict__ b1,   const float* __restrict__ b2,
    const float* __restrict__ ln2g, const float* __restrict__ ln2b,
    float* __restrict__ hf, u16* __restrict__ hb, int M)
{
  __shared__ u16 lB[2][128*64];
  __shared__ u16 h1s[64*128];
  __shared__ u16 fs[64*128];
  __shared__ float lsum[64][2];
  __shared__ float lsq[64][2];

  const int tid  = threadIdx.x;
  const int lane = tid & 63;
  const int wid  = tid >> 6;
  const int wr   = wid >> 1, wc = wid & 1;
  const int m0   = blockIdx.x * 64;

  const int ldrow = lane >> 3;
  const int gran  = (lane & 7) ^ ldrow;

  const int rbase_l = wr*32 + ((lane >> 4) << 2);
  const int cbase   = wc*64 + (lane & 15);

  auto stage_issue = [&](int s) {
    u16* dst = lB[s & 1];
    #pragma unroll
    for (int is = 0; is < 4; is++) {
      const int r = wid*32 + is*8;
      const u16* gp;
      if (s < 2) gp = Wo + (size_t)(r + ldrow)*128 + s*64;
      else {
        const int t = s - 2, c = t >> 2, k = t & 3;
        gp = (k < 2) ? (W1 + (size_t)(c*128 + r + ldrow)*128 + k*64)
                     : (W2 + (size_t)(r + ldrow)*512 + c*128 + (k-2)*64);
      }
      gload_lds16(gp + gran*8, dst + r*64);
    }
  };

  #pragma unroll
  for (int is = 0; is < 4; is++) {
    const int r0 = wid*16 + is*4;
    const int rr = r0 + (lane >> 4);
    int gm = m0 + rr; if (gm >= M) gm = M - 1;
    const int gsrc = ((lane & 7) ^ (rr & 7)) | (lane & 8);
    gload_lds16(savb + (size_t)gm*128 + gsrc*8, &fs[r0*128]);
  }
  stage_issue(0);

  f32x4 acc1[2][4], acc2[2][4], acc3[2][4];
  #pragma unroll
  for (int i = 0; i < 2; i++)
    #pragma unroll
    for (int j = 0; j < 4; j++) {
      acc1[i][j][0]=0.f; acc1[i][j][1]=0.f; acc1[i][j][2]=0.f; acc1[i][j][3]=0.f;
      acc3[i][j][0]=0.f; acc3[i][j][1]=0.f; acc3[i][j][2]=0.f; acc3[i][j][3]=0.f;
    }

  asm volatile("s_waitcnt vmcnt(0)" ::: "memory");
  __syncthreads();

  #pragma unroll
  for (int s = 0; s < 18; s++) {
    if (s < 17) stage_issue(s + 1);

    if (s >= 2 && ((s - 2) & 3) == 0) {
      #pragma unroll
      for (int i = 0; i < 2; i++)
        #pragma unroll
        for (int j = 0; j < 4; j++) { acc2[i][j][0]=0.f; acc2[i][j][1]=0.f; acc2[i][j][2]=0.f; acc2[i][j][3]=0.f; }
    }

    if (s < 2)
      mfma_stage64(fs,  lB[s & 1], lane, wr, wc, (s & 1)*8, acc1);
    else if (((s - 2) & 3) < 2)
      mfma_stage64(h1s, lB[s & 1], lane, wr, wc, (s & 1)*8, acc2);
    else
      mfma_stage64(fs,  lB[s & 1], lane, wr, wc, (s & 1)*8, acc3);

    if (s == 1) {
      #pragma unroll
      for (int mi = 0; mi < 2; mi++) {
        #pragma unroll
        for (int r = 0; r < 4; r++) {
          const int lrow = rbase_l + mi*16 + r;
          int gr = m0 + lrow; if (gr >= M) gr = M - 1;
          float ps = 0.f, pq = 0.f;
          #pragma unroll
          for (int ni = 0; ni < 4; ni++) {
            const int col = cbase + ni*16;
            float x = acc1[mi][ni][r] + hf[(size_t)gr*128 + col];
            acc1[mi][ni][r] = x;
            ps += x; pq += x*x;
          }
          #pragma unroll
          for (int off = 1; off < 16; off <<= 1) { ps += __shfl_xor(ps, off); pq += __shfl_xor(pq, off); }
          if ((lane & 15) == 0) { lsum[lrow][wc] = ps; lsq[lrow][wc] = pq; }
        }
      }
      __syncthreads();
      #pragma unroll
      for (int mi = 0; mi < 2; mi++) {
        #pragma unroll
        for (int r = 0; r < 4; r++) {
          const int lrow = rbase_l + mi*16 + r;
          const float mean = (lsum[lrow][0] + lsum[lrow][1]) * (1.0f/128.0f);
          float var = (lsq[lrow][0] + lsq[lrow][1]) * (1.0f/128.0f) - mean*mean;
          const float rstd = rsqrtf(fmaxf(var, 0.f) + LN_EPS);
          #pragma unroll
          for (int ni = 0; ni < 4; ni++) {
            const int col = cbase + ni*16;
            float o = (acc1[mi][ni][r] - mean) * rstd * ln1g[col] + ln1b[col];
            acc1[mi][ni][r] = o;
            const int g16 = col >> 3;
            const int slot = ((g16 & 7) ^ (lrow & 7)) | (g16 & 8);
            h1s[lrow*128 + slot*8 + (col & 7)] = f2bf(o);
          }
        }
      }
    } else if (s >= 2 && ((s - 2) & 3) == 1) {
      const int c = (s - 2) >> 2;
      #pragma unroll
      for (int mi = 0; mi < 2; mi++) {
        #pragma unroll
        for (int r = 0; r < 4; r++) {
          const int lrow = rbase_l + mi*16 + r;
          #pragma unroll
          for (int ni = 0; ni < 4; ni++) {
            const int col = cbase + ni*16;
            float v = fmaxf(acc2[mi][ni][r] + b1[c*128 + col], 0.f);
            const int g16 = col >> 3;
            const int slot = ((g16 & 7) ^ (lrow & 7)) | (g16 & 8);
            fs[lrow*128 + slot*8 + (col & 7)] = f2bf(v);
          }
        }
      }
    }

    if (s < 17) {
      asm volatile("s_waitcnt vmcnt(0)" ::: "memory");
      __syncthreads();
    }
  }

  #pragma unroll
  for (int mi = 0; mi < 2; mi++) {
    #pragma unroll
    for (int r = 0; r < 4; r++) {
      const int lrow = rbase_l + mi*16 + r;
      float ps = 0.f, pq = 0.f;
      #pragma unroll
      for (int ni = 0; ni < 4; ni++) {
        const int col = cbase + ni*16;
        float x = acc3[mi][ni][r] + b2[col] + acc1[mi][ni][r];
        acc3[mi][ni][r] = x;
        ps += x; pq += x*x;
      }
      #pragma unroll
      for (int off = 1; off < 16; off <<= 1) { ps += __shfl_xor(ps, off); pq += __shfl_xor(pq, off); }
      if ((lane & 15) == 0) { lsum[lrow][wc] = ps; lsq[lrow][wc] = pq; }
    }
  }
  __syncthreads();
  #pragma unroll
  for (int mi = 0; mi < 2; mi++) {
    #pragma unroll
    for (int r = 0; r < 4; r++) {
      const int lrow = rbase_l + mi*16 + r;
      const int grow = m0 + lrow;
      if (grow >= M) continue;
      const float mean = (lsum[lrow][0] + lsum[lrow][1]) * (1.0f/128.0f);
      float var = (lsq[lrow][0] + lsq[lrow][1]) * (1.0f/128.0f) - mean*mean;
      const float rstd = rsqrtf(fmaxf(var, 0.f) + LN_EPS);
      #pragma unroll
      for (int ni = 0; ni < 4; ni++) {
        const int col = cbase + ni*16;
        float o = (acc3[mi][ni][r] - mean) * rstd * ln2g[col] + ln2b[col];
        hf[(size_t)grow*128 + col] = o;
        hb[(size_t)grow*128 + col] = f2bf(o);
      }
    }
  }
}

// ---------------- attention: single-pass, constant-shift softmax, 8-deep MLP ----------------
__global__ __launch_bounds__(256) void attn_kernel(
    const float* __restrict__ q, const u16* __restrict__ kv,
    const int* __restrict__ offs, const int* __restrict__ csr_src,
    u16* __restrict__ outb, int N)
{
  const int tid = threadIdx.x;
  const int j   = tid & 15;
  const int n   = blockIdx.x*16 + (tid >> 4);
  if (n >= N) return;

  float qreg[8];
  *(float4*)&qreg[0] = ld4(&q[(size_t)n*128 + j*8]);
  *(float4*)&qreg[4] = ld4(&q[(size_t)n*128 + j*8 + 4]);

  const int start = offs[n];
  const int deg   = offs[n+1] - start;

  float s = 0.f;
  float acc[8] = {0,0,0,0,0,0,0,0};
  const int gb = tid & 48;

  for (int base = 0; base < deg; base += 16) {
    const int myidx = base + j;
    const int sn_mine = (myidx < deg) ? csr_src[start + myidx] : 0;
    const int cnt = (deg - base < 16) ? (deg - base) : 16;

    for (int b2 = 0; b2 < cnt; b2 += 8) {
      const int m8 = cnt - b2;
      uint4 K4[8], V4[8];
      #pragma unroll
      for (int u = 0; u < 8; u++) {
        const int sel = b2 + ((u < m8) ? u : 0);
        const int sn = __shfl(sn_mine, gb + sel);
        const u16* row = kv + (size_t)sn*256 + j*8;
        K4[u] = *(const uint4*)row;
        V4[u] = *(const uint4*)(row + 128);
      }
      #pragma unroll
      for (int u = 0; u < 8; u++) {
        if (u < m8) {
          float d = bl(K4[u].x)*qreg[0] + bh(K4[u].x)*qreg[1]
                  + bl(K4[u].y)*qreg[2] + bh(K4[u].y)*qreg[3]
                  + bl(K4[u].z)*qreg[4] + bh(K4[u].z)*qreg[5]
                  + bl(K4[u].w)*qreg[6] + bh(K4[u].w)*qreg[7];
          d += __shfl_xor(d, 1);
          float uu = fminf(fmaxf(d * 0.25f, -CLAMP_V), CLAMP_V);
          float e = __expf(uu - CLAMP_V);
          s += e;
          acc[0] = fmaf(e, bl(V4[u].x), acc[0]);
          acc[1] = fmaf(e, bh(V4[u].x), acc[1]);
          acc[2] = fmaf(e, bl(V4[u].y), acc[2]);
          acc[3] = fmaf(e, bh(V4[u].y), acc[3]);
          acc[4] = fmaf(e, bl(V4[u].z), acc[4]);
          acc[5] = fmaf(e, bh(V4[u].z), acc[5]);
          acc[6] = fmaf(e, bl(V4[u].w), acc[6]);
          acc[7] = fmaf(e, bh(V4[u].w), acc[7]);
        }
      }
    }
  }

  const float rs = (deg > 0) ? (1.0f / s) : 0.f;
  u16 o[8];
  #pragma unroll
  for (int t = 0; t < 8; t++) o[t] = f2bf(acc[t] * rs);
  *(uint4*)&outb[(size_t)n*128 + j*8] = *(const uint4*)o;
}

// ---------------- decoder + mean ----------------
__global__ __launch_bounds__(256) void dec_partial(const float* __restrict__ h,
    const float* __restrict__ W, float* __restrict__ partials, int N)
{
  float acc = 0.f;
  for (int n = blockIdx.x*256 + threadIdx.x; n < N; n += 256*256) {
    const float* hr = h + (size_t)n*D;
    float s = 0.f;
    #pragma unroll
    for (int t = 0; t < 32; t++) {
      float4 hv = ld4(&hr[t*4]); float4 wv = ld4(&W[t*4]);
      s += hv.x*wv.x + hv.y*wv.y + hv.z*wv.z + hv.w*wv.w;
    }
    acc += s;
  }
  #pragma unroll
  for (int off = 1; off < 64; off <<= 1) acc += __shfl_xor(acc, off);
  __shared__ float red[4];
  int lane = threadIdx.x & 63, w = threadIdx.x >> 6;
  if (lane == 0) red[w] = acc;
  __syncthreads();
  if (threadIdx.x == 0) partials[blockIdx.x] = red[0]+red[1]+red[2]+red[3];
}

__global__ __launch_bounds__(256) void dec_final(const float* __restrict__ partials,
    const float* __restrict__ decb, float* __restrict__ out, int N)
{
  float a = partials[threadIdx.x];
  #pragma unroll
  for (int off = 1; off < 64; off <<= 1) a += __shfl_xor(a, off);
  __shared__ float red[4];
  int lane = threadIdx.x & 63, w = threadIdx.x >> 6;
  if (lane == 0) red[w] = a;
  __syncthreads();
  if (threadIdx.x == 0) out[0] = (red[0]+red[1]+red[2]+red[3]) / (float)N + decb[0];
}

// ---------------- launch ----------------
extern "C" void kernel_launch(void* const* d_in, const int* in_sizes, int n_in,
                              void* d_out, int out_size, void* d_ws, size_t ws_size,
                              hipStream_t stream)
{
  const float* nf   = (const float*)d_in[0];
  const int*   src  = (const int*)  d_in[1];
  const int*   dst  = (const int*)  d_in[2];
  const float* encW = (const float*)d_in[3];
  const float* encb = (const float*)d_in[4];
  const float* Wq   = (const float*)d_in[5];
  const float* Wk   = (const float*)d_in[6];
  const float* Wv   = (const float*)d_in[7];
  const float* Wo   = (const float*)d_in[8];
  const float* ln1g = (const float*)d_in[9];
  const float* ln1b = (const float*)d_in[10];
  const float* W1   = (const float*)d_in[11];
  const float* b1   = (const float*)d_in[12];
  const float* W2   = (const float*)d_in[13];
  const float* b2   = (const float*)d_in[14];
  const float* ln2g = (const float*)d_in[15];
  const float* ln2b = (const float*)d_in[16];
  const float* decW = (const float*)d_in[17];
  const float* decb = (const float*)d_in[18];
  float* out = (float*)d_out;

  const int N = in_sizes[0] / 16;
  const int E = in_sizes[1];
  const int NB = (N + 1023) / 1024;

  float* ws   = (float*)d_ws;
  float* h    = ws;                              // [N,128] f32
  float* q    = h  + (size_t)N*128;              // [N,128] f32
  u16*  hb    = (u16*)(q + (size_t)N*128);       // [N,128] bf16
  u16*  kvb   = hb  + (size_t)N*128;             // [N,256] bf16 (k | v)
  u16*  savb  = kvb + (size_t)N*256;             // [N,128] bf16 (attn out)
  int* deg    = (int*)(savb + (size_t)N*128);
  int* offs   = deg + N;
  int* cursor = offs + N + 1;
  int* csr    = cursor + N;                      // holds src-node ids
  int* bsum   = csr + E;
  float* partials = (float*)(bsum + ((NB + 255) & ~255));
  u16* wbuf   = (u16*)(partials + 512);          // bf16 weights
  u16* wqkv   = wbuf;                            // [3][384][128]
  u16* wo_b   = wbuf + 147456;                   // [3][128][128]
  u16* w1_b   = wbuf + 196608;                   // [3][512][128]
  u16* w2_b   = wbuf + 393216;                   // [3][128][512]

  hipMemsetAsync(deg, 0, sizeof(int)*N, stream);
  count_kernel<<<(E+255)/256, 256, 0, stream>>>(dst, deg, E);
  scan_bsum<<<NB, 256, 0, stream>>>(deg, bsum, N);
  scan_bbase<<<1, 64, 0, stream>>>(bsum, NB);
  scan_write<<<NB, 256, 0, stream>>>(deg, bsum, offs, cursor, N);
  fill_kernel<<<(E+255)/256, 256, 0, stream>>>(dst, src, cursor, csr, E);

  convert_weights<<<(589824+255)/256, 256, 0, stream>>>(Wq, Wk, Wv, Wo, W1, W2, wbuf);

  encoder_kernel<<<(N+1)/2, 256, 0, stream>>>(nf, encW, encb, h, hb, N);

  const int gmx = (N + 127)/128;
  for (int l = 0; l < LAYERS; l++) {
    const u16* wqkv_l = wqkv + (size_t)l*384*128;
    const u16* wo_l   = wo_b + (size_t)l*128*128;
    const u16* w1_l   = w1_b + (size_t)l*512*128;
    const u16* w2_l   = w2_b + (size_t)l*128*512;

    gemm_qkv<<<gmx, 256, 0, stream>>>(hb, wqkv_l, q, kvb, N);

    attn_kernel<<<(N+15)/16, 256, 0, stream>>>(q, kvb, offs, csr, savb, N);

    ffn_fused<<<(N+63)/64, 256, 0, stream>>>(
        savb, wo_l, w1_l, w2_l,
        ln1g + l*D, ln1b + l*D, b1 + l*DFF, b2 + l*D, ln2g + l*D, ln2b + l*D,
        h, hb, N);
  }

  dec_partial<<<256, 256, 0, stream>>>(h, decW, partials, N);
  dec_final<<<1, 256, 0, stream>>>(partials, decb, out, N);
}

// Round 10
// 539.790 us; speedup vs baseline: 1.4179x; 1.0041x over previous
//
#include <hip/hip_runtime.h>
#include <math.h>

static constexpr int D   = 128;
static constexpr int DFF = 512;
static constexpr int LAYERS = 3;
static constexpr float CLAMP_V = 5.0f;
static constexpr float LN_EPS = 1e-5f;

typedef unsigned short u16;
typedef unsigned int   u32;
typedef short bf16x8 __attribute__((ext_vector_type(8)));
typedef float f32x4  __attribute__((ext_vector_type(4)));

__device__ inline float4 ld4(const float* p){ return *reinterpret_cast<const float4*>(p); }
__device__ inline u16 f2bf(float f){ u32 u = __float_as_uint(f); return (u16)((u + 0x7fff + ((u>>16)&1)) >> 16); }
__device__ inline float bl(u32 u){ return __uint_as_float(u << 16); }
__device__ inline float bh(u32 u){ return __uint_as_float(u & 0xffff0000u); }

__device__ inline void gload_lds16(const void* g, void* l) {
  __builtin_amdgcn_global_load_lds(
      (const __attribute__((address_space(1))) void*)g,
      (__attribute__((address_space(3))) void*)l, 16, 0, 0);
}

// ---------------- CSR build ----------------
__global__ __launch_bounds__(256) void count_kernel(const int* __restrict__ dst,
                                                    int* __restrict__ deg, int E)
{
  int e = blockIdx.x*256 + threadIdx.x;
  if (e < E) atomicAdd(&deg[dst[e]], 1);
}

__global__ __launch_bounds__(256) void scan_bsum(const int* __restrict__ deg,
                                                 int* __restrict__ bsum, int N)
{
  const int i0 = blockIdx.x*1024 + threadIdx.x*4;
  int s = 0;
  if (i0 + 3 < N) { int4 v = *(const int4*)&deg[i0]; s = v.x+v.y+v.z+v.w; }
  else { for (int t = 0; t < 4; t++) if (i0+t < N) s += deg[i0+t]; }
  #pragma unroll
  for (int off = 1; off < 64; off <<= 1) s += __shfl_xor(s, off);
  __shared__ int ws_[4];
  if ((threadIdx.x & 63) == 0) ws_[threadIdx.x >> 6] = s;
  __syncthreads();
  if (threadIdx.x == 0) bsum[blockIdx.x] = ws_[0]+ws_[1]+ws_[2]+ws_[3];
}

__global__ __launch_bounds__(64) void scan_bbase(int* __restrict__ bsum, int NB)
{
  const int tid = threadIdx.x;
  int base = 0;
  for (int c = 0; c < NB; c += 64) {
    const int idx = c + tid;
    int v = (idx < NB) ? bsum[idx] : 0;
    const int orig = v;
    #pragma unroll
    for (int off = 1; off < 64; off <<= 1) {
      int t = __shfl_up(v, off);
      if (tid >= off) v += t;
    }
    if (idx < NB) bsum[idx] = base + v - orig;
    base += __shfl(v, 63);
  }
}

__global__ __launch_bounds__(256) void scan_write(const int* __restrict__ deg,
    const int* __restrict__ bbase, int* __restrict__ offs, int* __restrict__ cursor, int N)
{
  const int i0 = blockIdx.x*1024 + threadIdx.x*4;
  int v[4] = {0,0,0,0};
  if (i0 + 3 < N) { int4 t = *(const int4*)&deg[i0]; v[0]=t.x; v[1]=t.y; v[2]=t.z; v[3]=t.w; }
  else { for (int t = 0; t < 4; t++) if (i0+t < N) v[t] = deg[i0+t]; }
  const int s = v[0]+v[1]+v[2]+v[3];
  const int lane = threadIdx.x & 63, w = threadIdx.x >> 6;
  int inc = s;
  #pragma unroll
  for (int off = 1; off < 64; off <<= 1) {
    int t = __shfl_up(inc, off);
    if (lane >= off) inc += t;
  }
  __shared__ int wsum[4];
  if (lane == 63) wsum[w] = inc;
  __syncthreads();
  int wb = 0;
  for (int t = 0; t < 4; t++) if (t < w) wb += wsum[t];
  int run = bbase[blockIdx.x] + wb + inc - s;
  #pragma unroll
  for (int t = 0; t < 4; t++) {
    if (i0 + t < N) { offs[i0+t] = run; cursor[i0+t] = run; run += v[t]; }
  }
  if (i0 <= N-1 && N-1 < i0+4) offs[N] = run;
}

__global__ __launch_bounds__(256) void fill_kernel(const int* __restrict__ dst,
    const int* __restrict__ src, int* __restrict__ cursor, int* __restrict__ csr_src, int E)
{
  int e = blockIdx.x*256 + threadIdx.x;
  if (e < E) {
    int p = atomicAdd(&cursor[dst[e]], 1);
    csr_src[p] = src[e];
  }
}

// ---------------- weight conversion to bf16 ----------------
__global__ __launch_bounds__(256) void convert_weights(
    const float* __restrict__ Wq, const float* __restrict__ Wk, const float* __restrict__ Wv,
    const float* __restrict__ Wo, const float* __restrict__ W1, const float* __restrict__ W2,
    u16* __restrict__ out)
{
  const int SQKV = 3*384*128;
  const int SWO  = 3*128*128;
  const int SW1  = 3*512*128;
  const int SW2  = 3*128*512;
  int i = blockIdx.x*256 + threadIdx.x;
  if (i >= SQKV+SWO+SW1+SW2) return;
  float v;
  if (i < SQKV) {
    int l = i / (384*128), rem = i % (384*128);
    int row = rem / 128, col = rem % 128;
    const float* W = (row < 128) ? Wq : ((row < 256) ? Wk : Wv);
    v = W[(size_t)l*128*128 + (size_t)(row & 127)*128 + col];
  } else if (i < SQKV+SWO) {
    v = Wo[i - SQKV];
  } else if (i < SQKV+SWO+SW1) {
    v = W1[i - SQKV - SWO];
  } else {
    v = W2[i - SQKV - SWO - SW1];
  }
  out[i] = f2bf(v);
}

// ---------------- encoder (f32 + bf16 dual write) ----------------
__global__ __launch_bounds__(256) void encoder_kernel(
    const float* __restrict__ nf, const float* __restrict__ W,
    const float* __restrict__ b, float* __restrict__ h, u16* __restrict__ hb, int N)
{
  int n = blockIdx.x*2 + (threadIdx.x >> 7);
  int d = threadIdx.x & 127;
  if (n >= N) return;
  const float* nr = nf + (size_t)n*16;
  const float* wr = W  + (size_t)d*16;
  float s = b[d];
  #pragma unroll
  for (int kk = 0; kk < 16; kk++) s = fmaf(nr[kk], wr[kk], s);
  h[(size_t)n*D + d]  = s;
  hb[(size_t)n*D + d] = f2bf(s);
}

// ---------------- MFMA helpers ----------------
__device__ inline void mfma_step128(const u16* __restrict__ la, const u16* __restrict__ lb,
                                    int lane, int wr, int wc, f32x4 (&acc)[4][4])
{
  #pragma unroll
  for (int k2 = 0; k2 < 2; k2++) {
    bf16x8 af[4], bfr[4];
    const int kq = k2*4 + (lane >> 4);
    #pragma unroll
    for (int mi = 0; mi < 4; mi++) {
      const int r = wr*64 + mi*16 + (lane & 15);
      af[mi] = *(const bf16x8*)&la[r*64 + ((kq ^ (r & 7)) << 3)];
    }
    #pragma unroll
    for (int ni = 0; ni < 4; ni++) {
      const int r = wc*64 + ni*16 + (lane & 15);
      bfr[ni] = *(const bf16x8*)&lb[r*64 + ((kq ^ (r & 7)) << 3)];
    }
    #pragma unroll
    for (int mi = 0; mi < 4; mi++)
      #pragma unroll
      for (int ni = 0; ni < 4; ni++)
        acc[mi][ni] = __builtin_amdgcn_mfma_f32_16x16x32_bf16(af[mi], bfr[ni], acc[mi][ni], 0, 0, 0);
  }
}

__device__ inline void mfma_stage64(const u16* __restrict__ Atile, const u16* __restrict__ Btile,
                                    int lane, int wr, int wc, int kabase, f32x4 (&acc)[2][4])
{
  #pragma unroll
  for (int k2 = 0; k2 < 2; k2++) {
    const int kql = k2*4 + (lane >> 4);
    const int kqa = kabase + kql;
    bf16x8 af[2], bfr[4];
    #pragma unroll
    for (int mi = 0; mi < 2; mi++) {
      const int r = wr*32 + mi*16 + (lane & 15);
      const int slot = ((kqa & 7) ^ (r & 7)) | (kqa & 8);
      af[mi] = *(const bf16x8*)&Atile[r*128 + slot*8];
    }
    #pragma unroll
    for (int ni = 0; ni < 4; ni++) {
      const int r = wc*64 + ni*16 + (lane & 15);
      bfr[ni] = *(const bf16x8*)&Btile[r*64 + ((kql ^ (r & 7)) << 3)];
    }
    #pragma unroll
    for (int mi = 0; mi < 2; mi++)
      #pragma unroll
      for (int ni = 0; ni < 4; ni++)
        acc[mi][ni] = __builtin_amdgcn_mfma_f32_16x16x32_bf16(af[mi], bfr[ni], acc[mi][ni], 0, 0, 0);
  }
}

// ---------------- QKV GEMM: A staged once, 3 weight mats, 2-deep counted-vmcnt ----------------
__global__ __launch_bounds__(256) void gemm_qkv(
    const u16* __restrict__ A, const u16* __restrict__ B,
    float* __restrict__ qf, u16* __restrict__ kvb, int M)
{
  __shared__ u16 lA[2][128*64];
  __shared__ u16 lW[2][128*64];
  const int m0 = blockIdx.x * 128;
  const int tid = threadIdx.x, lane = tid & 63, wid = tid >> 6;
  const int wr = wid >> 1, wc = wid & 1;
  const int ldrow = lane >> 3;
  const int gran  = (lane & 7) ^ ldrow;

  auto issueA = [&](int ks) {
    const int k0 = ks*64 + gran*8;
    #pragma unroll
    for (int is = 0; is < 4; is++) {
      const int r = wid*32 + is*8;
      int gm = m0 + r + ldrow; if (gm >= M) gm = M - 1;
      gload_lds16(A + (size_t)gm*128 + k0, &lA[ks][r*64]);
    }
  };
  auto issueW = [&](int s) {
    const u16* Bm = B + (size_t)(s >> 1)*128*128;
    const int k0 = (s & 1)*64 + gran*8;
    #pragma unroll
    for (int is = 0; is < 4; is++) {
      const int r = wid*32 + is*8;
      gload_lds16(Bm + (size_t)(r + ldrow)*128 + k0, &lW[s & 1][r*64]);
    }
  };

  // 2-deep prologue: A (both halves) + W stages 0 and 1
  issueA(0); issueA(1); issueW(0); issueW(1);   // 16 outstanding
  asm volatile("s_waitcnt vmcnt(4)" ::: "memory");  // A + W0 landed (W1 may remain)
  __builtin_amdgcn_s_barrier();

  f32x4 acc[4][4];
  const int rbase = m0 + wr*64 + ((lane >> 4) << 2);
  const int cbase = wc*64 + (lane & 15);

  #pragma unroll
  for (int s = 0; s < 6; s++) {
    if ((s & 1) == 0) {
      #pragma unroll
      for (int i = 0; i < 4; i++)
        #pragma unroll
        for (int j = 0; j < 4; j++) { acc[i][j][0]=0.f; acc[i][j][1]=0.f; acc[i][j][2]=0.f; acc[i][j][3]=0.f; }
    }
    mfma_step128(lA[s & 1], lW[s & 1], lane, wr, wc, acc);
    if (s & 1) {
      const int mat = s >> 1;
      #pragma unroll
      for (int ni = 0; ni < 4; ni++) {
        const int col = cbase + ni*16;
        #pragma unroll
        for (int mi = 0; mi < 4; mi++) {
          #pragma unroll
          for (int r = 0; r < 4; r++) {
            const int gm = rbase + mi*16 + r;
            if (gm < M) {
              if (mat == 0) qf[(size_t)gm*128 + col] = acc[mi][ni][r];
              else          kvb[(size_t)gm*256 + (mat-1)*128 + col] = f2bf(acc[mi][ni][r]);
            }
          }
        }
      }
    }
    if (s < 5) {
      asm volatile("s_waitcnt lgkmcnt(0)" ::: "memory");
      __builtin_amdgcn_s_barrier();                     // buffer lW[s&1] free
      if (s < 4) issueW(s + 2);                         // overwrite lW[s&1]
      if (s == 4) { asm volatile("s_waitcnt vmcnt(0)" ::: "memory"); }
      else        { asm volatile("s_waitcnt vmcnt(4)" ::: "memory"); }  // s+1 loads landed
      __builtin_amdgcn_s_barrier();
    }
  }
}

// ---------------- fused per-layer tail, 18-stage 2-deep counted-vmcnt pipeline ----------------
__global__ __launch_bounds__(256) void ffn_fused(
    const u16* __restrict__ savb, const u16* __restrict__ Wo,
    const u16* __restrict__ W1,   const u16* __restrict__ W2,
    const float* __restrict__ ln1g, const float* __restrict__ ln1b,
    const float* __restrict__ b1,   const float* __restrict__ b2,
    const float* __restrict__ ln2g, const float* __restrict__ ln2b,
    float* __restrict__ hf, u16* __restrict__ hb, int M)
{
  __shared__ u16 lB[2][128*64];
  __shared__ u16 h1s[64*128];
  __shared__ u16 fs[64*128];
  __shared__ float lsum[64][2];
  __shared__ float lsq[64][2];

  const int tid  = threadIdx.x;
  const int lane = tid & 63;
  const int wid  = tid >> 6;
  const int wr   = wid >> 1, wc = wid & 1;
  const int m0   = blockIdx.x * 64;

  const int ldrow = lane >> 3;
  const int gran  = (lane & 7) ^ ldrow;

  const int rbase_l = wr*32 + ((lane >> 4) << 2);
  const int cbase   = wc*64 + (lane & 15);

  auto stage_issue = [&](int s) {
    u16* dst = lB[s & 1];
    #pragma unroll
    for (int is = 0; is < 4; is++) {
      const int r = wid*32 + is*8;
      const u16* gp;
      if (s < 2) gp = Wo + (size_t)(r + ldrow)*128 + s*64;
      else {
        const int t = s - 2, c = t >> 2, k = t & 3;
        gp = (k < 2) ? (W1 + (size_t)(c*128 + r + ldrow)*128 + k*64)
                     : (W2 + (size_t)(r + ldrow)*512 + c*128 + (k-2)*64);
      }
      gload_lds16(gp + gran*8, dst + r*64);
    }
  };

  // prologue: A-slab (into fs) + stages 0,1 (2-deep)
  #pragma unroll
  for (int is = 0; is < 4; is++) {
    const int r0 = wid*16 + is*4;
    const int rr = r0 + (lane >> 4);
    int gm = m0 + rr; if (gm >= M) gm = M - 1;
    const int gsrc = ((lane & 7) ^ (rr & 7)) | (lane & 8);
    gload_lds16(savb + (size_t)gm*128 + gsrc*8, &fs[r0*128]);
  }
  stage_issue(0);
  stage_issue(1);                                     // 12 outstanding
  asm volatile("s_waitcnt vmcnt(4)" ::: "memory");    // A-slab + stage0 landed
  __builtin_amdgcn_s_barrier();

  f32x4 acc1[2][4], acc2[2][4], acc3[2][4];
  #pragma unroll
  for (int i = 0; i < 2; i++)
    #pragma unroll
    for (int j = 0; j < 4; j++) {
      acc1[i][j][0]=0.f; acc1[i][j][1]=0.f; acc1[i][j][2]=0.f; acc1[i][j][3]=0.f;
      acc3[i][j][0]=0.f; acc3[i][j][1]=0.f; acc3[i][j][2]=0.f; acc3[i][j][3]=0.f;
    }

  #pragma unroll
  for (int s = 0; s < 18; s++) {
    if (s >= 2 && ((s - 2) & 3) == 0) {
      #pragma unroll
      for (int i = 0; i < 2; i++)
        #pragma unroll
        for (int j = 0; j < 4; j++) { acc2[i][j][0]=0.f; acc2[i][j][1]=0.f; acc2[i][j][2]=0.f; acc2[i][j][3]=0.f; }
    }

    if (s < 2)
      mfma_stage64(fs,  lB[s & 1], lane, wr, wc, (s & 1)*8, acc1);
    else if (((s - 2) & 3) < 2)
      mfma_stage64(h1s, lB[s & 1], lane, wr, wc, (s & 1)*8, acc2);
    else
      mfma_stage64(fs,  lB[s & 1], lane, wr, wc, (s & 1)*8, acc3);

    if (s == 1) {
      // LN1: x = uh + h_res ; h1 -> acc1 (f32) + h1s (bf16)
      #pragma unroll
      for (int mi = 0; mi < 2; mi++) {
        #pragma unroll
        for (int r = 0; r < 4; r++) {
          const int lrow = rbase_l + mi*16 + r;
          int gr = m0 + lrow; if (gr >= M) gr = M - 1;
          float ps = 0.f, pq = 0.f;
          #pragma unroll
          for (int ni = 0; ni < 4; ni++) {
            const int col = cbase + ni*16;
            float x = acc1[mi][ni][r] + hf[(size_t)gr*128 + col];
            acc1[mi][ni][r] = x;
            ps += x; pq += x*x;
          }
          #pragma unroll
          for (int off = 1; off < 16; off <<= 1) { ps += __shfl_xor(ps, off); pq += __shfl_xor(pq, off); }
          if ((lane & 15) == 0) { lsum[lrow][wc] = ps; lsq[lrow][wc] = pq; }
        }
      }
      __syncthreads();
      #pragma unroll
      for (int mi = 0; mi < 2; mi++) {
        #pragma unroll
        for (int r = 0; r < 4; r++) {
          const int lrow = rbase_l + mi*16 + r;
          const float mean = (lsum[lrow][0] + lsum[lrow][1]) * (1.0f/128.0f);
          float var = (lsq[lrow][0] + lsq[lrow][1]) * (1.0f/128.0f) - mean*mean;
          const float rstd = rsqrtf(fmaxf(var, 0.f) + LN_EPS);
          #pragma unroll
          for (int ni = 0; ni < 4; ni++) {
            const int col = cbase + ni*16;
            float o = (acc1[mi][ni][r] - mean) * rstd * ln1g[col] + ln1b[col];
            acc1[mi][ni][r] = o;
            const int g16 = col >> 3;
            const int slot = ((g16 & 7) ^ (lrow & 7)) | (g16 & 8);
            h1s[lrow*128 + slot*8 + (col & 7)] = f2bf(o);
          }
        }
      }
    } else if (s >= 2 && ((s - 2) & 3) == 1) {
      const int c = (s - 2) >> 2;
      #pragma unroll
      for (int mi = 0; mi < 2; mi++) {
        #pragma unroll
        for (int r = 0; r < 4; r++) {
          const int lrow = rbase_l + mi*16 + r;
          #pragma unroll
          for (int ni = 0; ni < 4; ni++) {
            const int col = cbase + ni*16;
            float v = fmaxf(acc2[mi][ni][r] + b1[c*128 + col], 0.f);
            const int g16 = col >> 3;
            const int slot = ((g16 & 7) ^ (lrow & 7)) | (g16 & 8);
            fs[lrow*128 + slot*8 + (col & 7)] = f2bf(v);
          }
        }
      }
    }

    if (s < 17) {
      asm volatile("s_waitcnt lgkmcnt(0)" ::: "memory");
      __builtin_amdgcn_s_barrier();                    // lB[s&1] free; epilogue LDS visible
      if (s < 16) stage_issue(s + 2);                  // overwrite lB[s&1]
      if (s == 16) { asm volatile("s_waitcnt vmcnt(0)" ::: "memory"); }
      else         { asm volatile("s_waitcnt vmcnt(4)" ::: "memory"); }  // s+1 loads landed
      __builtin_amdgcn_s_barrier();
    }
  }

  // LN2 epilogue
  #pragma unroll
  for (int mi = 0; mi < 2; mi++) {
    #pragma unroll
    for (int r = 0; r < 4; r++) {
      const int lrow = rbase_l + mi*16 + r;
      float ps = 0.f, pq = 0.f;
      #pragma unroll
      for (int ni = 0; ni < 4; ni++) {
        const int col = cbase + ni*16;
        float x = acc3[mi][ni][r] + b2[col] + acc1[mi][ni][r];
        acc3[mi][ni][r] = x;
        ps += x; pq += x*x;
      }
      #pragma unroll
      for (int off = 1; off < 16; off <<= 1) { ps += __shfl_xor(ps, off); pq += __shfl_xor(pq, off); }
      if ((lane & 15) == 0) { lsum[lrow][wc] = ps; lsq[lrow][wc] = pq; }
    }
  }
  __syncthreads();
  #pragma unroll
  for (int mi = 0; mi < 2; mi++) {
    #pragma unroll
    for (int r = 0; r < 4; r++) {
      const int lrow = rbase_l + mi*16 + r;
      const int grow = m0 + lrow;
      if (grow >= M) continue;
      const float mean = (lsum[lrow][0] + lsum[lrow][1]) * (1.0f/128.0f);
      float var = (lsq[lrow][0] + lsq[lrow][1]) * (1.0f/128.0f) - mean*mean;
      const float rstd = rsqrtf(fmaxf(var, 0.f) + LN_EPS);
      #pragma unroll
      for (int ni = 0; ni < 4; ni++) {
        const int col = cbase + ni*16;
        float o = (acc3[mi][ni][r] - mean) * rstd * ln2g[col] + ln2b[col];
        hf[(size_t)grow*128 + col] = o;
        hb[(size_t)grow*128 + col] = f2bf(o);
      }
    }
  }
}

// ---------------- attention: single-pass, constant-shift softmax, 8-deep MLP ----------------
__global__ __launch_bounds__(256) void attn_kernel(
    const float* __restrict__ q, const u16* __restrict__ kv,
    const int* __restrict__ offs, const int* __restrict__ csr_src,
    u16* __restrict__ outb, int N)
{
  const int tid = threadIdx.x;
  const int j   = tid & 15;
  const int n   = blockIdx.x*16 + (tid >> 4);
  if (n >= N) return;

  float qreg[8];
  *(float4*)&qreg[0] = ld4(&q[(size_t)n*128 + j*8]);
  *(float4*)&qreg[4] = ld4(&q[(size_t)n*128 + j*8 + 4]);

  const int start = offs[n];
  const int deg   = offs[n+1] - start;

  float s = 0.f;
  float acc[8] = {0,0,0,0,0,0,0,0};
  const int gb = tid & 48;

  for (int base = 0; base < deg; base += 16) {
    const int myidx = base + j;
    const int sn_mine = (myidx < deg) ? csr_src[start + myidx] : 0;
    const int cnt = (deg - base < 16) ? (deg - base) : 16;

    for (int b2 = 0; b2 < cnt; b2 += 8) {
      const int m8 = cnt - b2;
      uint4 K4[8], V4[8];
      #pragma unroll
      for (int u = 0; u < 8; u++) {
        const int sel = b2 + ((u < m8) ? u : 0);
        const int sn = __shfl(sn_mine, gb + sel);
        const u16* row = kv + (size_t)sn*256 + j*8;
        K4[u] = *(const uint4*)row;
        V4[u] = *(const uint4*)(row + 128);
      }
      #pragma unroll
      for (int u = 0; u < 8; u++) {
        if (u < m8) {
          float d = bl(K4[u].x)*qreg[0] + bh(K4[u].x)*qreg[1]
                  + bl(K4[u].y)*qreg[2] + bh(K4[u].y)*qreg[3]
                  + bl(K4[u].z)*qreg[4] + bh(K4[u].z)*qreg[5]
                  + bl(K4[u].w)*qreg[6] + bh(K4[u].w)*qreg[7];
          d += __shfl_xor(d, 1);
          float uu = fminf(fmaxf(d * 0.25f, -CLAMP_V), CLAMP_V);
          float e = __expf(uu - CLAMP_V);
          s += e;
          acc[0] = fmaf(e, bl(V4[u].x), acc[0]);
          acc[1] = fmaf(e, bh(V4[u].x), acc[1]);
          acc[2] = fmaf(e, bl(V4[u].y), acc[2]);
          acc[3] = fmaf(e, bh(V4[u].y), acc[3]);
          acc[4] = fmaf(e, bl(V4[u].z), acc[4]);
          acc[5] = fmaf(e, bh(V4[u].z), acc[5]);
          acc[6] = fmaf(e, bl(V4[u].w), acc[6]);
          acc[7] = fmaf(e, bh(V4[u].w), acc[7]);
        }
      }
    }
  }

  const float rs = (deg > 0) ? (1.0f / s) : 0.f;
  u16 o[8];
  #pragma unroll
  for (int t = 0; t < 8; t++) o[t] = f2bf(acc[t] * rs);
  *(uint4*)&outb[(size_t)n*128 + j*8] = *(const uint4*)o;
}

// ---------------- decoder + mean ----------------
__global__ __launch_bounds__(256) void dec_partial(const float* __restrict__ h,
    const float* __restrict__ W, float* __restrict__ partials, int N)
{
  float acc = 0.f;
  for (int n = blockIdx.x*256 + threadIdx.x; n < N; n += 256*256) {
    const float* hr = h + (size_t)n*D;
    float s = 0.f;
    #pragma unroll
    for (int t = 0; t < 32; t++) {
      float4 hv = ld4(&hr[t*4]); float4 wv = ld4(&W[t*4]);
      s += hv.x*wv.x + hv.y*wv.y + hv.z*wv.z + hv.w*wv.w;
    }
    acc += s;
  }
  #pragma unroll
  for (int off = 1; off < 64; off <<= 1) acc += __shfl_xor(acc, off);
  __shared__ float red[4];
  int lane = threadIdx.x & 63, w = threadIdx.x >> 6;
  if (lane == 0) red[w] = acc;
  __syncthreads();
  if (threadIdx.x == 0) partials[blockIdx.x] = red[0]+red[1]+red[2]+red[3];
}

__global__ __launch_bounds__(256) void dec_final(const float* __restrict__ partials,
    const float* __restrict__ decb, float* __restrict__ out, int N)
{
  float a = partials[threadIdx.x];
  #pragma unroll
  for (int off = 1; off < 64; off <<= 1) a += __shfl_xor(a, off);
  __shared__ float red[4];
  int lane = threadIdx.x & 63, w = threadIdx.x >> 6;
  if (lane == 0) red[w] = a;
  __syncthreads();
  if (threadIdx.x == 0) out[0] = (red[0]+red[1]+red[2]+red[3]) / (float)N + decb[0];
}

// ---------------- launch ----------------
extern "C" void kernel_launch(void* const* d_in, const int* in_sizes, int n_in,
                              void* d_out, int out_size, void* d_ws, size_t ws_size,
                              hipStream_t stream)
{
  const float* nf   = (const float*)d_in[0];
  const int*   src  = (const int*)  d_in[1];
  const int*   dst  = (const int*)  d_in[2];
  const float* encW = (const float*)d_in[3];
  const float* encb = (const float*)d_in[4];
  const float* Wq   = (const float*)d_in[5];
  const float* Wk   = (const float*)d_in[6];
  const float* Wv   = (const float*)d_in[7];
  const float* Wo   = (const float*)d_in[8];
  const float* ln1g = (const float*)d_in[9];
  const float* ln1b = (const float*)d_in[10];
  const float* W1   = (const float*)d_in[11];
  const float* b1   = (const float*)d_in[12];
  const float* W2   = (const float*)d_in[13];
  const float* b2   = (const float*)d_in[14];
  const float* ln2g = (const float*)d_in[15];
  const float* ln2b = (const float*)d_in[16];
  const float* decW = (const float*)d_in[17];
  const float* decb = (const float*)d_in[18];
  float* out = (float*)d_out;

  const int N = in_sizes[0] / 16;
  const int E = in_sizes[1];
  const int NB = (N + 1023) / 1024;

  float* ws   = (float*)d_ws;
  float* h    = ws;                              // [N,128] f32
  float* q    = h  + (size_t)N*128;              // [N,128] f32
  u16*  hb    = (u16*)(q + (size_t)N*128);       // [N,128] bf16
  u16*  kvb   = hb  + (size_t)N*128;             // [N,256] bf16 (k | v)
  u16*  savb  = kvb + (size_t)N*256;             // [N,128] bf16 (attn out)
  int* deg    = (int*)(savb + (size_t)N*128);
  int* offs   = deg + N;
  int* cursor = offs + N + 1;
  int* csr    = cursor + N;                      // holds src-node ids
  int* bsum   = csr + E;
  float* partials = (float*)(bsum + ((NB + 255) & ~255));
  u16* wbuf   = (u16*)(partials + 512);          // bf16 weights
  u16* wqkv   = wbuf;                            // [3][384][128]
  u16* wo_b   = wbuf + 147456;                   // [3][128][128]
  u16* w1_b   = wbuf + 196608;                   // [3][512][128]
  u16* w2_b   = wbuf + 393216;                   // [3][128][512]

  hipMemsetAsync(deg, 0, sizeof(int)*N, stream);
  count_kernel<<<(E+255)/256, 256, 0, stream>>>(dst, deg, E);
  scan_bsum<<<NB, 256, 0, stream>>>(deg, bsum, N);
  scan_bbase<<<1, 64, 0, stream>>>(bsum, NB);
  scan_write<<<NB, 256, 0, stream>>>(deg, bsum, offs, cursor, N);
  fill_kernel<<<(E+255)/256, 256, 0, stream>>>(dst, src, cursor, csr, E);

  convert_weights<<<(589824+255)/256, 256, 0, stream>>>(Wq, Wk, Wv, Wo, W1, W2, wbuf);

  encoder_kernel<<<(N+1)/2, 256, 0, stream>>>(nf, encW, encb, h, hb, N);

  const int gmx = (N + 127)/128;
  for (int l = 0; l < LAYERS; l++) {
    const u16* wqkv_l = wqkv + (size_t)l*384*128;
    const u16* wo_l   = wo_b + (size_t)l*128*128;
    const u16* w1_l   = w1_b + (size_t)l*512*128;
    const u16* w2_l   = w2_b + (size_t)l*128*512;

    gemm_qkv<<<gmx, 256, 0, stream>>>(hb, wqkv_l, q, kvb, N);

    attn_kernel<<<(N+15)/16, 256, 0, stream>>>(q, kvb, offs, csr, savb, N);

    ffn_fused<<<(N+63)/64, 256, 0, stream>>>(
        savb, wo_l, w1_l, w2_l,
        ln1g + l*D, ln1b + l*D, b1 + l*DFF, b2 + l*D, ln2g + l*D, ln2b + l*D,
        h, hb, N);
  }

  dec_partial<<<256, 256, 0, stream>>>(h, decW, partials, N);
  dec_final<<<1, 256, 0, stream>>>(partials, decb, out, N);
}